// Round 7
// baseline (168.158 us; speedup 1.0000x reference)
//
#include <hip/hip_runtime.h>
#include <hip/hip_bf16.h>
#include <cstddef>
#include <cstdint>

#define D_MODEL   256
#define N_HEADS   8
#define N_LEVELS  4
#define N_POINTS  4
#define D_HEAD    32
#define HLP       128      // N_HEADS*N_LEVELS*N_POINTS
#define NBATCH    4
#define LQ        4096
#define S_LEN     7680     // 4096+2048+1024+512
#define QB        4        // queries per sample block

typedef __attribute__((ext_vector_type(8))) short  short8;
typedef __attribute__((ext_vector_type(4))) float  f32x4;
typedef __attribute__((ext_vector_type(8))) unsigned short ushort8;

__device__ __forceinline__ unsigned short f2bf(float x) {
    __hip_bfloat16 h = __float2bfloat16(x);
    return *reinterpret_cast<unsigned short*>(&h);
}
__device__ __forceinline__ float bf2f(unsigned short u) {
    unsigned int v = ((unsigned int)u) << 16;
    return *reinterpret_cast<float*>(&v);
}

__device__ __forceinline__ void gload_lds16(const void* g, void* l) {
    __builtin_amdgcn_global_load_lds(
        (const __attribute__((address_space(1))) void*)g,
        (__attribute__((address_space(3))) void*)l,
        16, 0, 0);
}

// ---------------------------------------------------------------------------
// Fused weight prep: transpose [K=256][N] fp32 -> [N][K=256] bf16 for
// W_v (z=0), [W_off|W_aw] concat (z=1), W_out (z=2). Block (0,0,1) also
// writes bcat = [b_off|b_aw]. Grid (4,4,3), 256 threads.
// ---------------------------------------------------------------------------
__global__ __launch_bounds__(256) void prep_kernel(
    const float* __restrict__ W_v,  const float* __restrict__ W_off,
    const float* __restrict__ W_aw, const float* __restrict__ W_out,
    const float* __restrict__ b_off, const float* __restrict__ b_aw,
    unsigned short* __restrict__ Wv_t, unsigned short* __restrict__ Wcat_t,
    unsigned short* __restrict__ Wout_t, float* __restrict__ bcat)
{
    __shared__ float t[64][65];
    const int z   = blockIdx.z;
    const int k0  = blockIdx.y * 64;
    const int n0  = blockIdx.x * 64;
    const int tid = threadIdx.x;

    const float* src; int srcN; int cs; unsigned short* dst;
    if (z == 0)      { src = W_v;   srcN = 256; cs = n0;       dst = Wv_t;  }
    else if (z == 2) { src = W_out; srcN = 256; cs = n0;       dst = Wout_t;}
    else if (n0 < 128){ src = W_off; srcN = 128; cs = n0;      dst = Wcat_t;}
    else             { src = W_aw;  srcN = 128; cs = n0 - 128; dst = Wcat_t;}

    #pragma unroll
    for (int i = 0; i < 16; ++i) {
        int idx = tid + i * 256;
        int kk = idx >> 6, nn = idx & 63;
        t[kk][nn] = src[(size_t)(k0 + kk) * srcN + cs + nn];
    }
    __syncthreads();
    #pragma unroll
    for (int i = 0; i < 16; ++i) {
        int idx = tid + i * 256;
        int nn = idx >> 6, kk = idx & 63;
        dst[(size_t)(n0 + nn) * 256 + k0 + kk] = f2bf(t[kk][nn]);
    }
    if (z == 1 && blockIdx.x == 0 && blockIdx.y == 0) {
        bcat[tid] = (tid < 128) ? b_off[tid] : b_aw[tid - 128];
    }
}

// ---------------------------------------------------------------------------
// Pipelined value-GEMM + P-GEMM. 128x128 tiles (LDS-balanced 2x2 wave grid:
// 4 A-frag + 4 B-frag ds_read_b128 per 16 MFMA), double-buffered LDS with
// ONE barrier per K-step. Grid 736 (480 value + 256 P jobs), 256 thr.
// job < 480 : value tile -> value3 bf16 [n][m][s][32]
// job >= 480: P tile     -> P fp32 [nq][256]
// A fp32 row-major converted in-register while staging; B bf16 via lds-DMA.
// ---------------------------------------------------------------------------
__global__ __launch_bounds__(256) void gemm_vp_kernel(
    const float* __restrict__ inflat, const float* __restrict__ query,
    const unsigned short* __restrict__ Wv_t, const unsigned short* __restrict__ Wcat_t,
    const float* __restrict__ b_v, const float* __restrict__ bcat,
    unsigned short* __restrict__ value3, float* __restrict__ P)
{
    __shared__ alignas(16) unsigned short Abuf[2][8][64][8];   // 2 x 8 KiB
    __shared__ alignas(16) unsigned short Bbuf[2][8][64][8];   // 2 x 8 KiB

    const int job = blockIdx.x;
    const bool is_val = (job < 480);
    const int jj   = is_val ? job : (job - 480);
    const int row0 = (jj >> 1) * 128;
    const int col0 = (jj & 1) * 128;
    const float* A = is_val ? inflat : query;
    const unsigned short* Bt = is_val ? Wv_t : Wcat_t;
    const float* bias = is_val ? b_v : bcat;

    const int tid  = threadIdx.x;
    const int lane = tid & 63;
    const int w    = tid >> 6;
    const int wm   = w & 1;
    const int wn   = w >> 1;
    const int lr   = lane & 15;
    const int lk   = (lane >> 4) * 8;

    // per-thread staging addresses (chunks c=0,1 -> frag im = w*2+c)
    const float* Ap0 = A + (size_t)(row0 + (w * 2 + 0) * 16 + lr) * 256 + lk;
    const float* Ap1 = A + (size_t)(row0 + (w * 2 + 1) * 16 + lr) * 256 + lk;
    const unsigned short* Bcol = Bt + (size_t)(col0 + lr) * 256 + lk;

    f32x4 acc[4][4] = {};

    // prologue: step-0 A regs + B DMA
    float4 a00 = *(const float4*)(Ap0), a01 = *(const float4*)(Ap0 + 4);
    float4 a10 = *(const float4*)(Ap1), a11 = *(const float4*)(Ap1 + 4);
    #pragma unroll
    for (int c = 0; c < 2; ++c) {
        const int im = w * 2 + c;
        gload_lds16(Bcol + (size_t)im * 16 * 256, &Bbuf[0][im][0][0]);
    }

    for (int kt = 0; kt < 8; ++kt) {
        const int cur = kt & 1;
        // pack A(kt) into frag-order LDS
        {
            short8 pk;
            pk[0] = (short)f2bf(a00.x); pk[1] = (short)f2bf(a00.y);
            pk[2] = (short)f2bf(a00.z); pk[3] = (short)f2bf(a00.w);
            pk[4] = (short)f2bf(a01.x); pk[5] = (short)f2bf(a01.y);
            pk[6] = (short)f2bf(a01.z); pk[7] = (short)f2bf(a01.w);
            *(short8*)&Abuf[cur][w * 2 + 0][lane][0] = pk;
            pk[0] = (short)f2bf(a10.x); pk[1] = (short)f2bf(a10.y);
            pk[2] = (short)f2bf(a10.z); pk[3] = (short)f2bf(a10.w);
            pk[4] = (short)f2bf(a11.x); pk[5] = (short)f2bf(a11.y);
            pk[6] = (short)f2bf(a11.z); pk[7] = (short)f2bf(a11.w);
            *(short8*)&Abuf[cur][w * 2 + 1][lane][0] = pk;
        }
        __syncthreads();   // drains B-DMA(kt) + A ds_writes

        if (kt < 7) {      // prefetch kt+1 after the barrier (overlaps MFMA)
            const int k1 = (kt + 1) * 32;
            a00 = *(const float4*)(Ap0 + k1); a01 = *(const float4*)(Ap0 + k1 + 4);
            a10 = *(const float4*)(Ap1 + k1); a11 = *(const float4*)(Ap1 + k1 + 4);
            #pragma unroll
            for (int c = 0; c < 2; ++c) {
                const int im = w * 2 + c;
                gload_lds16(Bcol + (size_t)im * 16 * 256 + k1, &Bbuf[1 - cur][im][0][0]);
            }
        }

        short8 af[4], bfr[4];
        #pragma unroll
        for (int i = 0; i < 4; ++i) af[i]  = *(const short8*)&Abuf[cur][wm * 4 + i][lane][0];
        #pragma unroll
        for (int j = 0; j < 4; ++j) bfr[j] = *(const short8*)&Bbuf[cur][wn * 4 + j][lane][0];

        #pragma unroll
        for (int i = 0; i < 4; ++i)
            #pragma unroll
            for (int j = 0; j < 4; ++j)
                acc[i][j] = __builtin_amdgcn_mfma_f32_16x16x32_bf16(
                    af[i], bfr[j], acc[i][j], 0, 0, 0);
        // no second barrier: next step writes the other buffer
    }

    const int prow = (lane >> 4) * 4;
    const int pcol = lane & 15;
    if (is_val) {
        // row = n*7680 + s (7680 = 60*128: blocks never straddle n)
        const int n  = row0 / S_LEN;
        const int s0 = row0 - n * S_LEN + wm * 64;
        #pragma unroll
        for (int j = 0; j < 4; ++j) {
            const int col = col0 + wn * 64 + j * 16 + pcol;   // 0..255
            const float bs = bias[col];
            const int m = col >> 5, d = col & 31;
            unsigned short* dst = value3 + ((size_t)(n * 8 + m) * S_LEN + s0) * 32 + d;
            #pragma unroll
            for (int i = 0; i < 4; ++i) {
                #pragma unroll
                for (int r = 0; r < 4; ++r) {
                    const int rl = i * 16 + prow + r;
                    dst[(size_t)rl * 32] = f2bf(acc[i][j][r] + bs);
                }
            }
        }
    } else {
        #pragma unroll
        for (int j = 0; j < 4; ++j) {
            const int col = col0 + wn * 64 + j * 16 + pcol;
            const float bs = bias[col];
            #pragma unroll
            for (int i = 0; i < 4; ++i) {
                #pragma unroll
                for (int r = 0; r < 4; ++r) {
                    const int row = row0 + wm * 64 + i * 16 + prow + r;
                    P[(size_t)row * 256 + col] = acc[i][j][r] + bs;
                }
            }
        }
    }
}

// ---------------------------------------------------------------------------
// Sampling + softmax. 4096 blocks x 128 thr, QB=4 queries/block
// (16 blocks/CU -> 32-wave occupancy for gather-latency hiding).
// blockIdx&7 -> (n, q-half): batch n's 3.93 MB value slice stays resident in
// the two XCDs serving it. Two barriers total; softmax computed redundantly
// in-register per gather lane group. Gathers issued 8-at-a-time (4-sample
// chunks) for memory-level parallelism.
// ---------------------------------------------------------------------------
__global__ __launch_bounds__(128) void sample_kernel(
    const float* __restrict__ P, const float* __restrict__ refp,
    const int* __restrict__ shapes, const int* __restrict__ lstart,
    const unsigned short* __restrict__ value3,
    unsigned short* __restrict__ tout)
{
    __shared__ int   sG0[QB][130];
    __shared__ float sW [QB][130];
    __shared__ float sA [QB][130];
    __shared__ int   glim[4];

    const int b    = blockIdx.x;       // 0..4095
    const int xcd  = b & 7;
    const int n    = xcd >> 1;
    const int half = xcd & 1;
    const int slot = b >> 3;           // 0..511
    const int q0   = (slot * 2 + half) * QB;
    const int nq0  = n * LQ + q0;
    const int tid  = threadIdx.x;

    if (tid < 4) glim[tid] = lstart[tid] + shapes[tid] - 1;

    // phase 1: 4 queries x 128 points
    #pragma unroll
    for (int it = 0; it < 4; ++it) {
        const int idx = tid + it * 128;   // 0..511
        const int q   = idx >> 7;
        const int j   = idx & 127;        // m*16 + l*4 + p
        const int l   = (j >> 2) & 3;
        const int nq  = nq0 + q;
        const float off   = __builtin_nontemporal_load(P + (size_t)nq * 256 + j);
        const float logit = __builtin_nontemporal_load(P + (size_t)nq * 256 + 128 + j);
        const float ref   = __builtin_nontemporal_load(refp + (size_t)nq * N_LEVELS + l);
        const int   sh    = shapes[l];
        const float Tf    = (float)sh;
        float x = ref * Tf + off - 0.5f;
        x = fminf(fmaxf(x, 0.0f), Tf - 1.0f);
        const float x0 = floorf(x);
        sG0[q][j] = (int)x0 + lstart[l];
        sW [q][j] = x - x0;
        sA [q][j] = logit;
    }
    __syncthreads();

    // phase 2: gather + in-register softmax + interpolate
    const int q  = tid >> 5;          // 0..3
    const int r  = tid & 31;
    const int m  = r >> 2;            // head
    const int ql = r & 3;             // 8-dim group
    const unsigned short* vb =
        value3 + (size_t)(n * 8 + m) * S_LEN * 32 + ql * 8;

    float e[16];
    float mx = -1e30f;
    #pragma unroll
    for (int i = 0; i < 16; ++i) { e[i] = sA[q][m * 16 + i]; mx = fmaxf(mx, e[i]); }
    float s = 0.f;
    #pragma unroll
    for (int i = 0; i < 16; ++i) { e[i] = __expf(e[i] - mx); s += e[i]; }
    const float rs = 1.0f / s;

    float acc[8] = {};
    #pragma unroll
    for (int c = 0; c < 4; ++c) {
        // issue 8 independent 16 B gathers, then consume
        ushort8 u0[4], u1[4];
        float   aw[4], wl[4];
        #pragma unroll
        for (int i4 = 0; i4 < 4; ++i4) {
            const int i = c * 4 + i4;
            const int j = m * 16 + i;
            aw[i4] = e[i] * rs;
            wl[i4] = sW[q][j];
            const int g0 = sG0[q][j];
            const int g1 = min(g0 + 1, glim[i >> 2]);
            u0[i4] = *(const ushort8*)(vb + (size_t)g0 * 32);
            u1[i4] = *(const ushort8*)(vb + (size_t)g1 * 32);
        }
        #pragma unroll
        for (int i4 = 0; i4 < 4; ++i4) {
            #pragma unroll
            for (int d = 0; d < 8; ++d) {
                const float v0 = bf2f(u0[i4][d]);
                const float v1 = bf2f(u1[i4][d]);
                acc[d] += aw[i4] * (v0 + wl[i4] * (v1 - v0));
            }
        }
    }
    ushort8 o;
    #pragma unroll
    for (int d = 0; d < 8; ++d) o[d] = f2bf(acc[d]);
    __builtin_nontemporal_store(o,
        (ushort8*)(tout + (size_t)(nq0 + q) * 256 + m * 32 + ql * 8));
}

// ---------------------------------------------------------------------------
// Pipelined out-proj GEMM: C[16384,256] = tbuf @ Wout_t^T + b_out (fp32 out).
// 64x128 tiles, grid 512 (2 blocks/CU), wave-tile 32x64 (2A+4B reads per
// 8 MFMA). Double-buffered, one barrier per K-step. A,B staged via lds-DMA.
// ---------------------------------------------------------------------------
__global__ __launch_bounds__(256) void gemm_out_kernel(
    const unsigned short* __restrict__ A,
    const unsigned short* __restrict__ Bt,
    const float* __restrict__ bias,
    float* __restrict__ Cout)
{
    __shared__ alignas(16) unsigned short Abuf[2][4][64][8];   // 2 x 4 KiB
    __shared__ alignas(16) unsigned short Bbuf[2][8][64][8];   // 2 x 8 KiB

    const int jj   = blockIdx.x;
    const int row0 = (jj >> 1) * 64;
    const int col0 = (jj & 1) * 128;

    const int tid  = threadIdx.x;
    const int lane = tid & 63;
    const int w    = tid >> 6;
    const int wm   = w & 1;        // row half (32 rows)
    const int wn   = w >> 1;       // col half (64 cols)
    const int lr   = lane & 15;
    const int lk   = (lane >> 4) * 8;

    // staging: wave w DMAs A-frag w (rows w*16..+15) and B-frags 2w, 2w+1
    const unsigned short* Arow = A + (size_t)(row0 + w * 16 + lr) * 256 + lk;
    const unsigned short* Bcol = Bt + (size_t)(col0 + lr) * 256 + lk;

    f32x4 acc[2][4] = {};

    gload_lds16(Arow, &Abuf[0][w][0][0]);
    #pragma unroll
    for (int c = 0; c < 2; ++c) {
        const int im = w * 2 + c;
        gload_lds16(Bcol + (size_t)im * 16 * 256, &Bbuf[0][im][0][0]);
    }

    for (int kt = 0; kt < 8; ++kt) {
        const int cur = kt & 1;
        __syncthreads();

        if (kt < 7) {
            const int k1 = (kt + 1) * 32;
            gload_lds16(Arow + k1, &Abuf[1 - cur][w][0][0]);
            #pragma unroll
            for (int c = 0; c < 2; ++c) {
                const int im = w * 2 + c;
                gload_lds16(Bcol + (size_t)im * 16 * 256 + k1, &Bbuf[1 - cur][im][0][0]);
            }
        }

        short8 af[2], bfr[4];
        #pragma unroll
        for (int i = 0; i < 2; ++i) af[i]  = *(const short8*)&Abuf[cur][wm * 2 + i][lane][0];
        #pragma unroll
        for (int j = 0; j < 4; ++j) bfr[j] = *(const short8*)&Bbuf[cur][wn * 4 + j][lane][0];

        #pragma unroll
        for (int i = 0; i < 2; ++i)
            #pragma unroll
            for (int j = 0; j < 4; ++j)
                acc[i][j] = __builtin_amdgcn_mfma_f32_16x16x32_bf16(
                    af[i], bfr[j], acc[i][j], 0, 0, 0);
    }

    const int prow = (lane >> 4) * 4;
    const int pcol = lane & 15;
    #pragma unroll
    for (int i = 0; i < 2; ++i) {
        #pragma unroll
        for (int j = 0; j < 4; ++j) {
            const int col = col0 + wn * 64 + j * 16 + pcol;
            const float bs = bias[col];
            const int rbase = row0 + wm * 32 + i * 16 + prow;
            #pragma unroll
            for (int r = 0; r < 4; ++r)
                Cout[(size_t)(rbase + r) * 256 + col] = acc[i][j][r] + bs;
        }
    }
}

// ---------------------------------------------------------------------------
extern "C" void kernel_launch(void* const* d_in, const int* in_sizes, int n_in,
                              void* d_out, int out_size, void* d_ws, size_t ws_size,
                              hipStream_t stream)
{
    const float* query  = (const float*)d_in[0];
    const float* refp   = (const float*)d_in[1];
    const float* inflat = (const float*)d_in[2];
    const int*   shapes = (const int*)d_in[3];
    const int*   lstart = (const int*)d_in[4];
    const float* W_off  = (const float*)d_in[5];
    const float* b_off  = (const float*)d_in[6];
    const float* W_aw   = (const float*)d_in[7];
    const float* b_aw   = (const float*)d_in[8];
    const float* W_v    = (const float*)d_in[9];
    const float* b_v    = (const float*)d_in[10];
    const float* W_out  = (const float*)d_in[11];
    const float* b_out  = (const float*)d_in[12];

    const int M_val = NBATCH * S_LEN;    // 30720
    const int M_q   = NBATCH * LQ;       // 16384

    // ---- workspace layout ----
    char* p = (char*)d_ws;
    unsigned short* value3 = (unsigned short*)p; p += (size_t)M_val * D_MODEL * 2; // 15.7 MB
    float*          P      = (float*)p;          p += (size_t)M_q * 256 * 4;       // 16.8 MB
    unsigned short* tbuf   = (unsigned short*)p; p += (size_t)M_q * D_MODEL * 2;   // 8.4 MB
    unsigned short* Wv_t   = (unsigned short*)p; p += 256 * 256 * 2;
    unsigned short* Wcat_t = (unsigned short*)p; p += 256 * 256 * 2;
    unsigned short* Wout_t = (unsigned short*)p; p += 256 * 256 * 2;
    float*          bcat   = (float*)p;          p += 256 * 4;

    // 1. weight prep
    prep_kernel<<<dim3(4, 4, 3), 256, 0, stream>>>(
        W_v, W_off, W_aw, W_out, b_off, b_aw, Wv_t, Wcat_t, Wout_t, bcat);
    // 2. value-GEMM (480 jobs) + P-GEMM (256 jobs), pipelined 128x128
    gemm_vp_kernel<<<736, 256, 0, stream>>>(
        inflat, query, Wv_t, Wcat_t, b_v, bcat, value3, P);
    // 3. sampling + softmax -> tbuf (bf16)
    sample_kernel<<<4096, 128, 0, stream>>>(
        P, refp, shapes, lstart, value3, tbuf);
    // 4. out = tbuf @ W_out + b_out (pipelined 64x128)
    gemm_out_kernel<<<512, 256, 0, stream>>>(
        tbuf, Wout_t, b_out, (float*)d_out);
}